// Round 10
// baseline (317.318 us; speedup 1.0000x reference)
//
#include <hip/hip_runtime.h>
#include <math.h>

#define BATCH 2
#define LSEQ  2048
#define TTOK  4096
#define DM    1024
#define DI    2048
#define NH    32
#define HP    64
#define NS    128
#define CONVD 2304
#define PROJ  4384
#define NCH   32
#define BLK   64

typedef __bf16 bf16x8 __attribute__((ext_vector_type(8)));
typedef float  f32x4  __attribute__((ext_vector_type(4)));
typedef unsigned short ushortx8 __attribute__((ext_vector_type(8)));
typedef unsigned short ushort_t;
typedef __attribute__((address_space(3))) void  lds_void;
typedef __attribute__((address_space(1))) const void glb_cvoid;

__device__ __forceinline__ float silu_(float x) { return x / (1.f + __expf(-x)); }

__device__ __forceinline__ unsigned short f2bf(float x) {
    union { float f; unsigned u; } u; u.f = x;
    unsigned r = u.u + 0x7fffu + ((u.u >> 16) & 1u);   // RNE
    return (unsigned short)(r >> 16);
}
__device__ __forceinline__ float bf2f(unsigned short s) {
    union { unsigned u; float f; } u; u.u = ((unsigned)s) << 16; return u.f;
}

// ---------------- fused cast: x, in_proj, out_proj -> bf16 ----------------
__global__ __launch_bounds__(256)
void cast_all_k(const float* __restrict__ x, const float* __restrict__ ipw,
                const float* __restrict__ opw,
                ushort_t* __restrict__ xb, ushort_t* __restrict__ ipb,
                ushort_t* __restrict__ opb)
{
    const int n1 = TTOK*DM, n2 = PROJ*DM;
    int i = (blockIdx.x * 256 + threadIdx.x) * 8;
    const float* src; ushort_t* dst;
    if (i < n1)            { src = x   + i;             dst = xb  + i; }
    else if (i < n1 + n2)  { src = ipw + (i - n1);      dst = ipb + (i - n1); }
    else                   { src = opw + (i - n1 - n2); dst = opb + (i - n1 - n2); }
    float4 a = *(const float4*)(src);
    float4 b = *(const float4*)(src + 4);
    ushortx8 r;
    r[0]=f2bf(a.x); r[1]=f2bf(a.y); r[2]=f2bf(a.z); r[3]=f2bf(a.w);
    r[4]=f2bf(b.x); r[5]=f2bf(b.y); r[6]=f2bf(b.z); r[7]=f2bf(b.w);
    *(ushortx8*)dst = r;
}

// ------- bf16 MFMA GEMM, tile TM x TN, BK=32, k-chunk-major LDS layout -------
// LDS layout: [rowhalf(64)][kc(4)][row&63][8 ushorts]. Staging thread t loads
// global row (t&63)+64j, kchunk t>>6 -> dest base_j + 16*t (wave-uniform + lane*16, OK
// for global_load_lds). Fragment b128 reads then hit 8 distinct bank-quads per
// 8-lane cycle group -> conflict-free (row-major 64B-stride layout was ~8-way).
template<int TM, int TN, int HASRES, int OUTBF>
__global__ __launch_bounds__(256)
void hgemm_nt(const ushort_t* __restrict__ A, const ushort_t* __restrict__ Bw,
              void* __restrict__ Cp, const float* __restrict__ R,
              int M, int N, int K)
{
    constexpr int MT = TM / 32, NT = TN / 32;
    constexpr int JA = TM / 64, JB = TN / 64;
    __shared__ ushort_t S[(TM + TN) * 32];
    ushort_t* As = S;
    ushort_t* Bs = S + TM * 32;
    char* As_c = (char*)As;
    char* Bs_c = (char*)Bs;
    const int t = threadIdx.x;
    const int l = t & 63, w = t >> 6;

    const int tx_ = (N + TN - 1) / TN, ty_ = (M + TM - 1) / TM;
    int bid = blockIdx.x;
    int sc = bid / (8 * ty_), rem = bid % (8 * ty_);
    int sw_w = min(8, tx_ - sc * 8);
    int bx = sc * 8 + rem % sw_w;
    int by = rem / sw_w;
    const int bm = by * TM, bn = bx * TN;
    const int wm = (w >> 1) * (TM / 2), wn = (w & 1) * (TN / 2);

    // staging: thread t covers global row (t&63)+64j, k-chunk (t>>6)*8
    const int rowt = t & 63;
    const int kkt  = (t >> 6) * 8;
    const ushort_t* srcA = A + (size_t)(bm + rowt) * K + kkt;
    const ushort_t* srcB[JB];
#pragma unroll
    for (int j = 0; j < JB; ++j) {
        int gr = min(bn + j * 64 + rowt, N - 1);
        srcB[j] = Bw + (size_t)gr * K + kkt;
    }

    f32x4 acc[MT][NT] = {};
    const int fr = l & 15, kc512 = (l >> 4) * 512;

    for (int k0 = 0; k0 < K; k0 += 32) {
        __syncthreads();
#pragma unroll
        for (int j = 0; j < JA; ++j)
            __builtin_amdgcn_global_load_lds((glb_cvoid*)(srcA + (size_t)j * 64 * K + k0),
                                             (lds_void*)(As_c + j * 4096 + 16 * t), 16, 0, 0);
#pragma unroll
        for (int j = 0; j < JB; ++j)
            __builtin_amdgcn_global_load_lds((glb_cvoid*)(srcB[j] + k0),
                                             (lds_void*)(Bs_c + j * 4096 + 16 * t), 16, 0, 0);
        __syncthreads();
        bf16x8 af[MT], bfr[NT];
#pragma unroll
        for (int mt = 0; mt < MT; ++mt) {
            int ar = wm + mt * 16 + fr;
            af[mt] = *(const bf16x8*)(As + (ar >> 6) * 2048 + kc512 + (ar & 63) * 8);
        }
#pragma unroll
        for (int nt = 0; nt < NT; ++nt) {
            int br = wn + nt * 16 + fr;
            bfr[nt] = *(const bf16x8*)(Bs + (br >> 6) * 2048 + kc512 + (br & 63) * 8);
        }
#pragma unroll
        for (int mt = 0; mt < MT; ++mt)
#pragma unroll
            for (int nt = 0; nt < NT; ++nt)
                acc[mt][nt] = __builtin_amdgcn_mfma_f32_16x16x32_bf16(af[mt], bfr[nt], acc[mt][nt], 0, 0, 0);
    }

    const int crow = (l >> 4) * 4, ccol = l & 15;
#pragma unroll
    for (int mt = 0; mt < MT; ++mt) {
#pragma unroll
        for (int nt = 0; nt < NT; ++nt) {
            int n = bn + wn + nt * 16 + ccol;
            if (n >= N) continue;
#pragma unroll
            for (int i = 0; i < 4; ++i) {
                int m = bm + wm + mt * 16 + crow + i;
                float v = acc[mt][nt][i];
                if (HASRES) v += R[(size_t)m * N + n];
                if (OUTBF) ((ushort_t*)Cp)[(size_t)m * N + n] = f2bf(v);
                else       ((float*)Cp)[(size_t)m * N + n] = v;
            }
        }
    }
}

// ---- fused: depthwise conv(K=4)+double silu (4 tokens/thread, 7 taps) | dt+cumA ----
#define NCONVB 2304   // (TTOK/4) * (CONVD/4) / 256
__global__ __launch_bounds__(256)
void mid1_k(const ushort_t* __restrict__ zx, const float* __restrict__ cw,
            const float* __restrict__ dt_bias, const float* __restrict__ A_log,
            ushort_t* __restrict__ xBC, float* __restrict__ dt_sp, float* __restrict__ cumA)
{
    if (blockIdx.x < NCONVB) {
        int idx = blockIdx.x * 256 + threadIdx.x;
        int c4 = (idx % (CONVD/4)) * 4;
        int g  = idx / (CONVD/4);
        int b = g >> 9, l0 = (g & 511) * 4;
        const ushort_t* col = zx + (size_t)b * LSEQ * PROJ + DI + c4;
        float4 w0 = *(const float4*)(cw + c4*4);
        float4 w1 = *(const float4*)(cw + c4*4 + 4);
        float4 w2 = *(const float4*)(cw + c4*4 + 8);
        float4 w3 = *(const float4*)(cw + c4*4 + 12);
        float rx[7][4];
#pragma unroll
        for (int k = 0; k < 7; ++k) {
            int l = l0 - 3 + k;
            if (l >= 0) {
                ushort4 v = *(const ushort4*)(col + (size_t)l * PROJ);
                rx[k][0]=bf2f(v.x); rx[k][1]=bf2f(v.y); rx[k][2]=bf2f(v.z); rx[k][3]=bf2f(v.w);
            } else {
                rx[k][0]=0.f; rx[k][1]=0.f; rx[k][2]=0.f; rx[k][3]=0.f;
            }
        }
        float wt[4][4] = {{w0.x,w0.y,w0.z,w0.w},{w1.x,w1.y,w1.z,w1.w},
                          {w2.x,w2.y,w2.z,w2.w},{w3.x,w3.y,w3.z,w3.w}};
#pragma unroll
        for (int i = 0; i < 4; ++i) {
            ushort4 o;
            float a[4];
#pragma unroll
            for (int ch = 0; ch < 4; ++ch) {
                a[ch] = wt[ch][0]*rx[i][ch] + wt[ch][1]*rx[i+1][ch]
                      + wt[ch][2]*rx[i+2][ch] + wt[ch][3]*rx[i+3][ch];
            }
            o.x = f2bf(silu_(silu_(a[0]))); o.y = f2bf(silu_(silu_(a[1])));
            o.z = f2bf(silu_(silu_(a[2]))); o.w = f2bf(silu_(silu_(a[3])));
            *(ushort4*)(xBC + (size_t)(b*LSEQ + l0 + i) * CONVD + c4) = o;
        }
    } else {
        int wid = (blockIdx.x - NCONVB) * 4 + (threadIdx.x >> 6);
        int ln = threadIdx.x & 63;
        int c = wid & 31, h = (wid >> 5) & 31, b = wid >> 10;
        int tk = b * LSEQ + c * BLK + ln;
        float xv = bf2f(zx[(size_t)tk * PROJ + (DI + CONVD) + h]) + dt_bias[h];
        float dtv = (xv > 20.f) ? xv : log1pf(__expf(xv));
        dt_sp[tk * NH + h] = dtv;
        float val = -__expf(A_log[h]) * dtv;
#pragma unroll
        for (int off = 1; off < 64; off <<= 1) {
            float u = __shfl_up(val, off, 64);
            if (ln >= off) val += u;
        }
        cumA[(size_t)wid * 64 + ln] = val;
    }
}

// -------- fused: CBT via MFMA (64 blocks) | chunk-states MFMA -> bf16 (2048 blocks) --------
__global__ __launch_bounds__(256)
void mid2_k(const ushort_t* __restrict__ xBC, const float* __restrict__ dt_sp,
            const float* __restrict__ cumA, ushort_t* __restrict__ CBT,
            ushort_t* __restrict__ states)
{
    __shared__ __align__(16) char smem[34816];
    int t = threadIdx.x, r = t >> 2, q = t & 3;
    if (blockIdx.x < 64) {
        // CBT[l,s] = sum_n C[l,n]*B[s,n]  (64x64x128 NT MFMA, stride-136 LDS)
        int b = blockIdx.x >> 5, c = blockIdx.x & 31;
        ushort_t* sCm = (ushort_t*)smem;          // [l][n] stride 136
        ushort_t* sBm = sCm + 64 * 136;           // [s][n] stride 136
        const ushort_t* xb = xBC + (size_t)(b * LSEQ + c * BLK) * CONVD;
        int row = t >> 2, j4 = t & 3;
#pragma unroll
        for (int jj = 0; jj < 4; ++jj) {
            int n0 = j4 * 32 + jj * 8;
            *(ushortx8*)&sCm[row*136 + n0] = *(const ushortx8*)(xb + (size_t)row*CONVD + DI + NS + n0);
            *(ushortx8*)&sBm[row*136 + n0] = *(const ushortx8*)(xb + (size_t)row*CONVD + DI      + n0);
        }
        __syncthreads();
        int ln = t & 63, w = t >> 6;
        int wm = (w >> 1) * 32, wn = (w & 1) * 32;
        int fr = ln & 15;
        f32x4 acc[2][2] = {};
#pragma unroll
        for (int ks = 0; ks < 4; ++ks) {
            int koff = ks*32 + (ln >> 4) * 8;
            bf16x8 af[2], bv[2];
#pragma unroll
            for (int mt = 0; mt < 2; ++mt) af[mt] = *(const bf16x8*)&sCm[(wm + mt*16 + fr)*136 + koff];
#pragma unroll
            for (int nt = 0; nt < 2; ++nt) bv[nt] = *(const bf16x8*)&sBm[(wn + nt*16 + fr)*136 + koff];
#pragma unroll
            for (int mt = 0; mt < 2; ++mt)
#pragma unroll
                for (int nt = 0; nt < 2; ++nt)
                    acc[mt][nt] = __builtin_amdgcn_mfma_f32_16x16x32_bf16(af[mt], bv[nt], acc[mt][nt], 0, 0, 0);
        }
        ushort_t* o = CBT + (size_t)blockIdx.x * 4096;
        int crow = (ln >> 4) * 4, ccol = ln & 15;
#pragma unroll
        for (int mt = 0; mt < 2; ++mt)
#pragma unroll
            for (int nt = 0; nt < 2; ++nt)
#pragma unroll
                for (int i = 0; i < 4; ++i)
                    o[(wm + mt*16 + crow + i)*64 + wn + nt*16 + ccol] = f2bf(acc[mt][nt][i]);
    } else {
        int bi = blockIdx.x - 64;            // b*1024 + c*32 + h
        int h = bi & 31, c = (bi >> 5) & 31, b = bi >> 10;
        ushort_t* XdT = (ushort_t*)smem;          // [p][l] stride 72
        ushort_t* BdT = XdT + 64 * 72;            // [n][l] stride 72
        const float* cA = cumA + (size_t)((b*NH + h)*NCH + c) * 64;
        float scale = dt_sp[(b * LSEQ + c * BLK + r) * NH + h] * __expf(cA[63] - cA[r]);
        const ushort_t* xb = xBC + (size_t)(b * LSEQ + c * BLK + r) * CONVD;
#pragma unroll
        for (int jj = 0; jj < 4; ++jj) {
            ushort4 v = *(const ushort4*)(xb + h*HP + q*16 + jj*4);
            int p0 = q*16 + jj*4;
            XdT[(p0+0)*72 + r] = v.x; XdT[(p0+1)*72 + r] = v.y;
            XdT[(p0+2)*72 + r] = v.z; XdT[(p0+3)*72 + r] = v.w;
        }
#pragma unroll
        for (int jj = 0; jj < 8; ++jj) {
            ushort4 v = *(const ushort4*)(xb + DI + q*32 + jj*4);
            int n0 = q*32 + jj*4;
            BdT[(n0+0)*72 + r] = f2bf(bf2f(v.x)*scale);
            BdT[(n0+1)*72 + r] = f2bf(bf2f(v.y)*scale);
            BdT[(n0+2)*72 + r] = f2bf(bf2f(v.z)*scale);
            BdT[(n0+3)*72 + r] = f2bf(bf2f(v.w)*scale);
        }
        __syncthreads();
        int ln = t & 63, w = t >> 6;
        int wm = (w >> 1) * 32, wn = (w & 1) * 64;
        int fr = ln & 15;
        f32x4 acc[2][4] = {};
#pragma unroll
        for (int ks = 0; ks < 2; ++ks) {
            int koff = ks*32 + (ln >> 4) * 8;
            bf16x8 af[2], bv[4];
#pragma unroll
            for (int mt = 0; mt < 2; ++mt) af[mt] = *(const bf16x8*)&XdT[(wm + mt*16 + fr)*72 + koff];
#pragma unroll
            for (int nt = 0; nt < 4; ++nt) bv[nt] = *(const bf16x8*)&BdT[(wn + nt*16 + fr)*72 + koff];
#pragma unroll
            for (int mt = 0; mt < 2; ++mt)
#pragma unroll
                for (int nt = 0; nt < 4; ++nt)
                    acc[mt][nt] = __builtin_amdgcn_mfma_f32_16x16x32_bf16(af[mt], bv[nt], acc[mt][nt], 0, 0, 0);
        }
        ushort_t* o = states + (size_t)((b*NCH + c)*NH + h) * 8192;
        int crow = (ln >> 4) * 4, ccol = ln & 15;
#pragma unroll
        for (int mt = 0; mt < 2; ++mt)
#pragma unroll
            for (int nt = 0; nt < 4; ++nt)
#pragma unroll
                for (int i = 0; i < 4; ++i)
                    o[(wm + mt*16 + crow + i)*128 + wn + nt*16 + ccol] = f2bf(acc[mt][nt][i]);
    }
}

// ---------------- inter-chunk scan, x4 vectorized ----------------
__global__ __launch_bounds__(256)
void scan_k(const float* __restrict__ init_state, const float* __restrict__ cumA,
            const ushort_t* __restrict__ states, ushort_t* __restrict__ pref,
            float* __restrict__ out_final)
{
    int idx = (blockIdx.x * 256 + threadIdx.x) * 4;
    int h = (idx >> 13) & 31, b = idx >> 18;
    int pn = idx & 8191;
    float4 run = *(const float4*)(init_state + idx);
    const float* cAb = cumA + (size_t)(b*NH + h) * NCH * 64;
    for (int c = 0; c < NCH; ++c) {
        float e = expf(cAb[c*64 + 63]);
        size_t off = (size_t)((b*NCH + c)*NH + h) * 8192 + pn;
        ushort4 s = *(const ushort4*)(states + off);
        ushort4 p;
        p.x = f2bf(run.x); p.y = f2bf(run.y); p.z = f2bf(run.z); p.w = f2bf(run.w);
        *(ushort4*)(pref + off) = p;
        run.x = e * run.x + bf2f(s.x);
        run.y = e * run.y + bf2f(s.y);
        run.z = e * run.z + bf2f(s.z);
        run.w = e * run.w + bf2f(s.w);
    }
    *(float4*)(out_final + idx) = run;
}

// ---------------- Y = Y_diag + Y_off + D*X via MFMA, bf16 out ----------------
__global__ __launch_bounds__(256)
void y_mfma_k(const ushort_t* __restrict__ xBC, const float* __restrict__ dt_sp,
              const float* __restrict__ cumA, const ushort_t* __restrict__ CBT,
              const ushort_t* __restrict__ pref, const float* __restrict__ D_param,
              ushort_t* __restrict__ Y)
{
    int bi = blockIdx.x;                 // b*1024 + c*32 + h
    int h = bi & 31, c = (bi >> 5) & 31, b = bi >> 10;
    __shared__ ushort_t Wm[64 * 72];     // [l][s] masked decay*CBT*dt[s]
    __shared__ ushort_t XT[64 * 72];     // [p][s] raw X
    __shared__ ushort_t Cd[64 * 136];    // [l][n] C*exp(cA)
    __shared__ ushort_t Sp[64 * 136];    // [p][n] bf16 prefix state
    __shared__ float sCA[64];
    __shared__ float sdt[64];
    int t = threadIdx.x, r = t >> 2, q = t & 3;
    const float* cA = cumA + (size_t)((b*NH + h)*NCH + c) * 64;
    if (t < 64) {
        sCA[t] = cA[t];
        sdt[t] = dt_sp[(b * LSEQ + c * BLK + t) * NH + h];
    }
    __syncthreads();
    size_t row = (size_t)(b * LSEQ + c * BLK + r);
    const ushort_t* xb = xBC + row * CONVD;
    float myA = sCA[r], eC = __expf(myA);
    const ushort_t* cbt = CBT + (size_t)(b*NCH + c) * 4096 + r * 64 + q * 16;
    {
        ushortx8 c0 = *(const ushortx8*)(cbt);
        ushortx8 c1 = *(const ushortx8*)(cbt + 8);
        ushortx8 w0, w1;
#pragma unroll
        for (int j = 0; j < 8; ++j) {
            int s0 = q*16 + j, s1 = q*16 + 8 + j;
            float v0 = (s0 <= r) ? bf2f(c0[j]) * __expf(myA - sCA[s0]) * sdt[s0] : 0.f;
            float v1 = (s1 <= r) ? bf2f(c1[j]) * __expf(myA - sCA[s1]) * sdt[s1] : 0.f;
            w0[j] = f2bf(v0); w1[j] = f2bf(v1);
        }
        *(ushortx8*)&Wm[r*72 + q*16] = w0;
        *(ushortx8*)&Wm[r*72 + q*16 + 8] = w1;
    }
#pragma unroll
    for (int jj = 0; jj < 4; ++jj) {
        ushort4 v = *(const ushort4*)(xb + h*HP + q*16 + jj*4);
        int p0 = q*16 + jj*4;
        XT[(p0+0)*72 + r] = v.x; XT[(p0+1)*72 + r] = v.y;
        XT[(p0+2)*72 + r] = v.z; XT[(p0+3)*72 + r] = v.w;
    }
#pragma unroll
    for (int jj = 0; jj < 8; ++jj) {
        ushort4 v = *(const ushort4*)(xb + DI + NS + q*32 + jj*4);
        int n0 = q*32 + jj*4;
        ushort4 o;
        o.x = f2bf(bf2f(v.x)*eC); o.y = f2bf(bf2f(v.y)*eC);
        o.z = f2bf(bf2f(v.z)*eC); o.w = f2bf(bf2f(v.w)*eC);
        *(ushort4*)&Cd[r*136 + n0] = o;
    }
    const ushort_t* pr = pref + (size_t)((b*NCH + c)*NH + h) * 8192 + r * 128;
#pragma unroll
    for (int jj = 0; jj < 4; ++jj) {
        ushortx8 v = *(const ushortx8*)(pr + q*32 + jj*8);
        *(ushortx8*)&Sp[r*136 + q*32 + jj*8] = v;
    }
    __syncthreads();
    int ln = t & 63, w = t >> 6;
    int wm = (w >> 1) * 32, wn = (w & 1) * 32;   // l-span 32, p-span 32
    int fr = ln & 15;
    f32x4 acc[2][2] = {};
#pragma unroll
    for (int ks = 0; ks < 2; ++ks) {            // Y_diag over s (K=64)
        int koff = ks*32 + (ln >> 4) * 8;
        bf16x8 af[2], bv[2];
#pragma unroll
        for (int mt = 0; mt < 2; ++mt) af[mt] = *(const bf16x8*)&Wm[(wm + mt*16 + fr)*72 + koff];
#pragma unroll
        for (int nt = 0; nt < 2; ++nt) bv[nt] = *(const bf16x8*)&XT[(wn + nt*16 + fr)*72 + koff];
#pragma unroll
        for (int mt = 0; mt < 2; ++mt)
#pragma unroll
            for (int nt = 0; nt < 2; ++nt)
                acc[mt][nt] = __builtin_amdgcn_mfma_f32_16x16x32_bf16(af[mt], bv[nt], acc[mt][nt], 0, 0, 0);
    }
#pragma unroll
    for (int ks = 0; ks < 4; ++ks) {            // Y_off over n (K=128)
        int koff = ks*32 + (ln >> 4) * 8;
        bf16x8 af[2], bv[2];
#pragma unroll
        for (int mt = 0; mt < 2; ++mt) af[mt] = *(const bf16x8*)&Cd[(wm + mt*16 + fr)*136 + koff];
#pragma unroll
        for (int nt = 0; nt < 2; ++nt) bv[nt] = *(const bf16x8*)&Sp[(wn + nt*16 + fr)*136 + koff];
#pragma unroll
        for (int mt = 0; mt < 2; ++mt)
#pragma unroll
            for (int nt = 0; nt < 2; ++nt)
                acc[mt][nt] = __builtin_amdgcn_mfma_f32_16x16x32_bf16(af[mt], bv[nt], acc[mt][nt], 0, 0, 0);
    }
    float Dh = D_param[h];
    int crow = (ln >> 4) * 4, ccol = ln & 15;
#pragma unroll
    for (int mt = 0; mt < 2; ++mt)
#pragma unroll
        for (int nt = 0; nt < 2; ++nt)
#pragma unroll
            for (int i = 0; i < 4; ++i) {
                int li = wm + mt*16 + crow + i;
                int p  = wn + nt*16 + ccol;
                size_t rr = (size_t)(b*LSEQ + c*BLK + li);
                float xv = bf2f(XT[p*72 + li]);   // X from LDS, not HBM
                Y[rr * DI + h*HP + p] = f2bf(acc[mt][nt][i] + Dh * xv);
            }
}

// ---------------- RMSNorm + sigmoid(z) gate (bf16 in) -> bf16 ----------------
__global__ __launch_bounds__(256)
void rms_gate_k(const ushort_t* __restrict__ zx, const float* __restrict__ norm_w,
                const ushort_t* __restrict__ Y, ushort_t* __restrict__ Yb)
{
    int tk = blockIdx.x, t = threadIdx.x;
    const ushort_t* rowp = Y + (size_t)tk * DI + t*8;
    ushortx8 v = *(const ushortx8*)rowp;
    float f[8];
    float ss = 0.f;
#pragma unroll
    for (int i = 0; i < 8; ++i) { f[i] = bf2f(v[i]); ss += f[i]*f[i]; }
#pragma unroll
    for (int off = 32; off > 0; off >>= 1) ss += __shfl_xor(ss, off, 64);
    __shared__ float sw[4];
    __shared__ float stot;
    if ((t & 63) == 0) sw[t >> 6] = ss;
    __syncthreads();
    if (t == 0) stot = rsqrtf((sw[0]+sw[1]+sw[2]+sw[3]) * (1.f/DI) + 1.1920929e-07f);
    __syncthreads();
    float scale = stot;
    const ushort_t* zr = zx + (size_t)tk * PROJ + t*8;
    ushortx8 z = *(const ushortx8*)zr;
    float4 w0 = *(const float4*)(norm_w + t*8);
    float4 w1 = *(const float4*)(norm_w + t*8 + 4);
    float wv[8] = {w0.x,w0.y,w0.z,w0.w,w1.x,w1.y,w1.z,w1.w};
    ushortx8 o;
#pragma unroll
    for (int i = 0; i < 8; ++i)
        o[i] = f2bf(f[i]*scale*wv[i] / (1.f+__expf(-bf2f(z[i]))));
    *(ushortx8*)(Yb + (size_t)tk * DI + t*8) = o;
}

extern "C" void kernel_launch(void* const* d_in, const int* in_sizes, int n_in,
                              void* d_out, int out_size, void* d_ws, size_t ws_size,
                              hipStream_t stream)
{
    const float* x        = (const float*)d_in[0];
    const float* init_st  = (const float*)d_in[1];
    const float* in_proj  = (const float*)d_in[2];
    const float* conv_w   = (const float*)d_in[3];
    const float* A_log    = (const float*)d_in[4];
    const float* dt_bias  = (const float*)d_in[5];
    const float* D_param  = (const float*)d_in[6];
    const float* norm_w   = (const float*)d_in[7];
    const float* out_proj = (const float*)d_in[8];
    float* out = (float*)d_out;

    ushort_t* zx_bf  = (ushort_t*)d_ws;                       // TTOK*PROJ
    ushort_t* xBC_bf = zx_bf + (size_t)TTOK*PROJ;             // TTOK*CONVD
    float* dt_sp  = (float*)(xBC_bf + (size_t)TTOK*CONVD);    // TTOK*NH
    float* cumA   = dt_sp  + (size_t)TTOK*NH;                 // 131072
    ushort_t* CBTb = (ushort_t*)(cumA + (size_t)TTOK*NH);     // 262144 bf16
    ushort_t* states = CBTb + 262144;                         // 16777216 (bf16)
    ushort_t* pref = states + 16777216;                       // 16777216 (bf16)
    float* Yreg   = (float*)(pref + 16777216);                // region
    ushort_t* opw_bf = (ushort_t*)(Yreg + (size_t)TTOK*DI);   // DM*DI
    ushort_t* Y_bf   = (ushort_t*)Yreg;                       // TTOK*DI bf16
    ushort_t* xb_bf  = (ushort_t*)Yreg;                       // TTOK*DM (alias, dead after gemm1)
    ushort_t* ipw_bf = xb_bf + (size_t)TTOK*DM;               // PROJ*DM (alias, dead after gemm1)
    ushort_t* Yb_bf  = xBC_bf;                                // alias, used after y_mfma

    const int nc = (TTOK*DM + PROJ*DM + DM*DI) / (256*8);
    cast_all_k<<<nc, 256, 0, stream>>>(x, in_proj, out_proj, xb_bf, ipw_bf, opw_bf);
    hgemm_nt<128,128,0,1><<<((PROJ+127)/128)*(TTOK/128), 256, 0, stream>>>(xb_bf, ipw_bf, zx_bf, nullptr, TTOK, PROJ, DM);
    mid1_k<<<NCONVB + BATCH*NH*NCH/4, 256, 0, stream>>>(zx_bf, conv_w, dt_bias, A_log, xBC_bf, dt_sp, cumA);
    mid2_k<<<64 + BATCH*NCH*NH, 256, 0, stream>>>(xBC_bf, dt_sp, cumA, CBTb, states);
    scan_k<<<(BATCH*NH*HP*NS)/(256*4), 256, 0, stream>>>(init_st, cumA, states, pref, out + (size_t)TTOK*DM);
    y_mfma_k<<<BATCH*NCH*NH, 256, 0, stream>>>(xBC_bf, dt_sp, cumA, CBTb, pref, D_param, Y_bf);
    rms_gate_k<<<TTOK, 256, 0, stream>>>(zx_bf, norm_w, Y_bf, Yb_bf);
    hgemm_nt<128,64,1,0><<<(DM/64)*(TTOK/128), 256, 0, stream>>>(Yb_bf, opw_bf, out, x, TTOK, DM, DI);
}

// Round 11
// 273.875 us; speedup vs baseline: 1.1586x; 1.1586x over previous
//
#include <hip/hip_runtime.h>
#include <math.h>

#define BATCH 2
#define LSEQ  2048
#define TTOK  4096
#define DM    1024
#define DI    2048
#define NH    32
#define HP    64
#define NS    128
#define CONVD 2304
#define PROJ  4384
#define NCH   32
#define BLK   64

typedef __bf16 bf16x8 __attribute__((ext_vector_type(8)));
typedef float  f32x4  __attribute__((ext_vector_type(4)));
typedef unsigned short ushortx8 __attribute__((ext_vector_type(8)));
typedef unsigned short ushort_t;
typedef __attribute__((address_space(3))) void  lds_void;
typedef __attribute__((address_space(1))) const void glb_cvoid;

__device__ __forceinline__ float silu_(float x) { return x / (1.f + __expf(-x)); }

__device__ __forceinline__ unsigned short f2bf(float x) {
    union { float f; unsigned u; } u; u.f = x;
    unsigned r = u.u + 0x7fffu + ((u.u >> 16) & 1u);   // RNE
    return (unsigned short)(r >> 16);
}
__device__ __forceinline__ float bf2f(unsigned short s) {
    union { unsigned u; float f; } u; u.u = ((unsigned)s) << 16; return u.f;
}

// ---------------- fused cast: x, in_proj, out_proj -> bf16 ----------------
__global__ __launch_bounds__(256)
void cast_all_k(const float* __restrict__ x, const float* __restrict__ ipw,
                const float* __restrict__ opw,
                ushort_t* __restrict__ xb, ushort_t* __restrict__ ipb,
                ushort_t* __restrict__ opb)
{
    const int n1 = TTOK*DM, n2 = PROJ*DM;
    int i = (blockIdx.x * 256 + threadIdx.x) * 8;
    const float* src; ushort_t* dst;
    if (i < n1)            { src = x   + i;             dst = xb  + i; }
    else if (i < n1 + n2)  { src = ipw + (i - n1);      dst = ipb + (i - n1); }
    else                   { src = opw + (i - n1 - n2); dst = opb + (i - n1 - n2); }
    float4 a = *(const float4*)(src);
    float4 b = *(const float4*)(src + 4);
    ushortx8 r;
    r[0]=f2bf(a.x); r[1]=f2bf(a.y); r[2]=f2bf(a.z); r[3]=f2bf(a.w);
    r[4]=f2bf(b.x); r[5]=f2bf(b.y); r[6]=f2bf(b.z); r[7]=f2bf(b.w);
    *(ushortx8*)dst = r;
}

// ------- bf16 MFMA GEMM, tile TM x TN, BK=32, XOR-swizzled k-chunks -------
// Staging: thread t loads row t>>2 (+64j), k-chunk (t&3)^((t>>2)&3). Same 64B
// contiguous global segment per 4-lane group as round-9 (coalescing intact);
// LDS image has per-row-rotated chunks -> fragment b128 reads are 2-way (free)
// instead of 8-way banked. Round-10 full-scatter proved conflicts=0 possible but
// lost coalescing (68->92us); this keeps both.
template<int TM, int TN, int HASRES, int OUTBF>
__global__ __launch_bounds__(256)
void hgemm_nt(const ushort_t* __restrict__ A, const ushort_t* __restrict__ Bw,
              void* __restrict__ Cp, const float* __restrict__ R,
              int M, int N, int K)
{
    constexpr int MT = TM / 32, NT = TN / 32;
    constexpr int JA = TM / 64, JB = TN / 64;
    __shared__ ushort_t S[(TM + TN) * 32];
    ushort_t* As = S;
    ushort_t* Bs = S + TM * 32;
    char* As_c = (char*)As;
    char* Bs_c = (char*)Bs;
    const int t = threadIdx.x;
    const int l = t & 63, w = t >> 6;

    const int tx_ = (N + TN - 1) / TN, ty_ = (M + TM - 1) / TM;
    int bid = blockIdx.x;
    int sc = bid / (8 * ty_), rem = bid % (8 * ty_);
    int sw_w = min(8, tx_ - sc * 8);
    int bx = sc * 8 + rem % sw_w;
    int by = rem / sw_w;
    const int bm = by * TM, bn = bx * TN;
    const int wm = (w >> 1) * (TM / 2), wn = (w & 1) * (TN / 2);

    // staging: thread t covers row t>>2 (+64j), k-chunk swizzled by row
    const int rowt = t >> 2;
    const int kkt  = (((t & 3) ^ (rowt & 3)) * 8);
    const ushort_t* srcA = A + (size_t)(bm + rowt) * K + kkt;
    const ushort_t* srcB[JB];
#pragma unroll
    for (int j = 0; j < JB; ++j) {
        int gr = min(bn + j * 64 + rowt, N - 1);
        srcB[j] = Bw + (size_t)gr * K + kkt;
    }

    f32x4 acc[MT][NT] = {};
    const int fr = l & 15;
    const int sw8 = (((l >> 4) ^ (fr & 3)) * 8);   // swizzled chunk offset (row&3 == fr&3)

    for (int k0 = 0; k0 < K; k0 += 32) {
        __syncthreads();
#pragma unroll
        for (int j = 0; j < JA; ++j)
            __builtin_amdgcn_global_load_lds((glb_cvoid*)(srcA + (size_t)j * 64 * K + k0),
                                             (lds_void*)(As_c + j * 4096 + 16 * t), 16, 0, 0);
#pragma unroll
        for (int j = 0; j < JB; ++j)
            __builtin_amdgcn_global_load_lds((glb_cvoid*)(srcB[j] + k0),
                                             (lds_void*)(Bs_c + j * 4096 + 16 * t), 16, 0, 0);
        __syncthreads();
        bf16x8 af[MT], bfr[NT];
#pragma unroll
        for (int mt = 0; mt < MT; ++mt)
            af[mt] = *(const bf16x8*)(As + (wm + mt * 16 + fr) * 32 + sw8);
#pragma unroll
        for (int nt = 0; nt < NT; ++nt)
            bfr[nt] = *(const bf16x8*)(Bs + (wn + nt * 16 + fr) * 32 + sw8);
#pragma unroll
        for (int mt = 0; mt < MT; ++mt)
#pragma unroll
            for (int nt = 0; nt < NT; ++nt)
                acc[mt][nt] = __builtin_amdgcn_mfma_f32_16x16x32_bf16(af[mt], bfr[nt], acc[mt][nt], 0, 0, 0);
    }

    const int crow = (l >> 4) * 4, ccol = l & 15;
#pragma unroll
    for (int mt = 0; mt < MT; ++mt) {
#pragma unroll
        for (int nt = 0; nt < NT; ++nt) {
            int n = bn + wn + nt * 16 + ccol;
            if (n >= N) continue;
#pragma unroll
            for (int i = 0; i < 4; ++i) {
                int m = bm + wm + mt * 16 + crow + i;
                float v = acc[mt][nt][i];
                if (HASRES) v += R[(size_t)m * N + n];
                if (OUTBF) ((ushort_t*)Cp)[(size_t)m * N + n] = f2bf(v);
                else       ((float*)Cp)[(size_t)m * N + n] = v;
            }
        }
    }
}

// ---- fused: depthwise conv(K=4)+double silu (4 tokens/thread, 7 taps) | dt+cumA ----
#define NCONVB 2304   // (TTOK/4) * (CONVD/4) / 256
__global__ __launch_bounds__(256)
void mid1_k(const ushort_t* __restrict__ zx, const float* __restrict__ cw,
            const float* __restrict__ dt_bias, const float* __restrict__ A_log,
            ushort_t* __restrict__ xBC, float* __restrict__ dt_sp, float* __restrict__ cumA)
{
    if (blockIdx.x < NCONVB) {
        int idx = blockIdx.x * 256 + threadIdx.x;
        int c4 = (idx % (CONVD/4)) * 4;
        int g  = idx / (CONVD/4);
        int b = g >> 9, l0 = (g & 511) * 4;
        const ushort_t* col = zx + (size_t)b * LSEQ * PROJ + DI + c4;
        float4 w0 = *(const float4*)(cw + c4*4);
        float4 w1 = *(const float4*)(cw + c4*4 + 4);
        float4 w2 = *(const float4*)(cw + c4*4 + 8);
        float4 w3 = *(const float4*)(cw + c4*4 + 12);
        float rx[7][4];
#pragma unroll
        for (int k = 0; k < 7; ++k) {
            int l = l0 - 3 + k;
            if (l >= 0) {
                ushort4 v = *(const ushort4*)(col + (size_t)l * PROJ);
                rx[k][0]=bf2f(v.x); rx[k][1]=bf2f(v.y); rx[k][2]=bf2f(v.z); rx[k][3]=bf2f(v.w);
            } else {
                rx[k][0]=0.f; rx[k][1]=0.f; rx[k][2]=0.f; rx[k][3]=0.f;
            }
        }
        float wt[4][4] = {{w0.x,w0.y,w0.z,w0.w},{w1.x,w1.y,w1.z,w1.w},
                          {w2.x,w2.y,w2.z,w2.w},{w3.x,w3.y,w3.z,w3.w}};
#pragma unroll
        for (int i = 0; i < 4; ++i) {
            ushort4 o;
            float a[4];
#pragma unroll
            for (int ch = 0; ch < 4; ++ch) {
                a[ch] = wt[ch][0]*rx[i][ch] + wt[ch][1]*rx[i+1][ch]
                      + wt[ch][2]*rx[i+2][ch] + wt[ch][3]*rx[i+3][ch];
            }
            o.x = f2bf(silu_(silu_(a[0]))); o.y = f2bf(silu_(silu_(a[1])));
            o.z = f2bf(silu_(silu_(a[2]))); o.w = f2bf(silu_(silu_(a[3])));
            *(ushort4*)(xBC + (size_t)(b*LSEQ + l0 + i) * CONVD + c4) = o;
        }
    } else {
        int wid = (blockIdx.x - NCONVB) * 4 + (threadIdx.x >> 6);
        int ln = threadIdx.x & 63;
        int c = wid & 31, h = (wid >> 5) & 31, b = wid >> 10;
        int tk = b * LSEQ + c * BLK + ln;
        float xv = bf2f(zx[(size_t)tk * PROJ + (DI + CONVD) + h]) + dt_bias[h];
        float dtv = (xv > 20.f) ? xv : log1pf(__expf(xv));
        dt_sp[tk * NH + h] = dtv;
        float val = -__expf(A_log[h]) * dtv;
#pragma unroll
        for (int off = 1; off < 64; off <<= 1) {
            float u = __shfl_up(val, off, 64);
            if (ln >= off) val += u;
        }
        cumA[(size_t)wid * 64 + ln] = val;
    }
}

// -------- fused: CBT via MFMA (64 blocks) | chunk-states MFMA -> bf16 (2048 blocks) --------
__global__ __launch_bounds__(256)
void mid2_k(const ushort_t* __restrict__ xBC, const float* __restrict__ dt_sp,
            const float* __restrict__ cumA, ushort_t* __restrict__ CBT,
            ushort_t* __restrict__ states)
{
    __shared__ __align__(16) char smem[34816];
    int t = threadIdx.x, r = t >> 2, q = t & 3;
    if (blockIdx.x < 64) {
        // CBT[l,s] = sum_n C[l,n]*B[s,n]  (64x64x128 NT MFMA, stride-136 LDS)
        int b = blockIdx.x >> 5, c = blockIdx.x & 31;
        ushort_t* sCm = (ushort_t*)smem;          // [l][n] stride 136
        ushort_t* sBm = sCm + 64 * 136;           // [s][n] stride 136
        const ushort_t* xb = xBC + (size_t)(b * LSEQ + c * BLK) * CONVD;
        int row = t >> 2, j4 = t & 3;
#pragma unroll
        for (int jj = 0; jj < 4; ++jj) {
            int n0 = j4 * 32 + jj * 8;
            *(ushortx8*)&sCm[row*136 + n0] = *(const ushortx8*)(xb + (size_t)row*CONVD + DI + NS + n0);
            *(ushortx8*)&sBm[row*136 + n0] = *(const ushortx8*)(xb + (size_t)row*CONVD + DI      + n0);
        }
        __syncthreads();
        int ln = t & 63, w = t >> 6;
        int wm = (w >> 1) * 32, wn = (w & 1) * 32;
        int fr = ln & 15;
        f32x4 acc[2][2] = {};
#pragma unroll
        for (int ks = 0; ks < 4; ++ks) {
            int koff = ks*32 + (ln >> 4) * 8;
            bf16x8 af[2], bv[2];
#pragma unroll
            for (int mt = 0; mt < 2; ++mt) af[mt] = *(const bf16x8*)&sCm[(wm + mt*16 + fr)*136 + koff];
#pragma unroll
            for (int nt = 0; nt < 2; ++nt) bv[nt] = *(const bf16x8*)&sBm[(wn + nt*16 + fr)*136 + koff];
#pragma unroll
            for (int mt = 0; mt < 2; ++mt)
#pragma unroll
                for (int nt = 0; nt < 2; ++nt)
                    acc[mt][nt] = __builtin_amdgcn_mfma_f32_16x16x32_bf16(af[mt], bv[nt], acc[mt][nt], 0, 0, 0);
        }
        ushort_t* o = CBT + (size_t)blockIdx.x * 4096;
        int crow = (ln >> 4) * 4, ccol = ln & 15;
#pragma unroll
        for (int mt = 0; mt < 2; ++mt)
#pragma unroll
            for (int nt = 0; nt < 2; ++nt)
#pragma unroll
                for (int i = 0; i < 4; ++i)
                    o[(wm + mt*16 + crow + i)*64 + wn + nt*16 + ccol] = f2bf(acc[mt][nt][i]);
    } else {
        int bi = blockIdx.x - 64;            // b*1024 + c*32 + h
        int h = bi & 31, c = (bi >> 5) & 31, b = bi >> 10;
        ushort_t* XdT = (ushort_t*)smem;          // [p][l] stride 72
        ushort_t* BdT = XdT + 64 * 72;            // [n][l] stride 72
        const float* cA = cumA + (size_t)((b*NH + h)*NCH + c) * 64;
        float scale = dt_sp[(b * LSEQ + c * BLK + r) * NH + h] * __expf(cA[63] - cA[r]);
        const ushort_t* xb = xBC + (size_t)(b * LSEQ + c * BLK + r) * CONVD;
#pragma unroll
        for (int jj = 0; jj < 4; ++jj) {
            ushort4 v = *(const ushort4*)(xb + h*HP + q*16 + jj*4);
            int p0 = q*16 + jj*4;
            XdT[(p0+0)*72 + r] = v.x; XdT[(p0+1)*72 + r] = v.y;
            XdT[(p0+2)*72 + r] = v.z; XdT[(p0+3)*72 + r] = v.w;
        }
#pragma unroll
        for (int jj = 0; jj < 8; ++jj) {
            ushort4 v = *(const ushort4*)(xb + DI + q*32 + jj*4);
            int n0 = q*32 + jj*4;
            BdT[(n0+0)*72 + r] = f2bf(bf2f(v.x)*scale);
            BdT[(n0+1)*72 + r] = f2bf(bf2f(v.y)*scale);
            BdT[(n0+2)*72 + r] = f2bf(bf2f(v.z)*scale);
            BdT[(n0+3)*72 + r] = f2bf(bf2f(v.w)*scale);
        }
        __syncthreads();
        int ln = t & 63, w = t >> 6;
        int wm = (w >> 1) * 32, wn = (w & 1) * 64;
        int fr = ln & 15;
        f32x4 acc[2][4] = {};
#pragma unroll
        for (int ks = 0; ks < 2; ++ks) {
            int koff = ks*32 + (ln >> 4) * 8;
            bf16x8 af[2], bv[4];
#pragma unroll
            for (int mt = 0; mt < 2; ++mt) af[mt] = *(const bf16x8*)&XdT[(wm + mt*16 + fr)*72 + koff];
#pragma unroll
            for (int nt = 0; nt < 4; ++nt) bv[nt] = *(const bf16x8*)&BdT[(wn + nt*16 + fr)*72 + koff];
#pragma unroll
            for (int mt = 0; mt < 2; ++mt)
#pragma unroll
                for (int nt = 0; nt < 4; ++nt)
                    acc[mt][nt] = __builtin_amdgcn_mfma_f32_16x16x32_bf16(af[mt], bv[nt], acc[mt][nt], 0, 0, 0);
        }
        ushort_t* o = states + (size_t)((b*NCH + c)*NH + h) * 8192;
        int crow = (ln >> 4) * 4, ccol = ln & 15;
#pragma unroll
        for (int mt = 0; mt < 2; ++mt)
#pragma unroll
            for (int nt = 0; nt < 4; ++nt)
#pragma unroll
                for (int i = 0; i < 4; ++i)
                    o[(wm + mt*16 + crow + i)*128 + wn + nt*16 + ccol] = f2bf(acc[mt][nt][i]);
    }
}

// ---------------- inter-chunk scan, x4 vectorized ----------------
__global__ __launch_bounds__(256)
void scan_k(const float* __restrict__ init_state, const float* __restrict__ cumA,
            const ushort_t* __restrict__ states, ushort_t* __restrict__ pref,
            float* __restrict__ out_final)
{
    int idx = (blockIdx.x * 256 + threadIdx.x) * 4;
    int h = (idx >> 13) & 31, b = idx >> 18;
    int pn = idx & 8191;
    float4 run = *(const float4*)(init_state + idx);
    const float* cAb = cumA + (size_t)(b*NH + h) * NCH * 64;
    for (int c = 0; c < NCH; ++c) {
        float e = expf(cAb[c*64 + 63]);
        size_t off = (size_t)((b*NCH + c)*NH + h) * 8192 + pn;
        ushort4 s = *(const ushort4*)(states + off);
        ushort4 p;
        p.x = f2bf(run.x); p.y = f2bf(run.y); p.z = f2bf(run.z); p.w = f2bf(run.w);
        *(ushort4*)(pref + off) = p;
        run.x = e * run.x + bf2f(s.x);
        run.y = e * run.y + bf2f(s.y);
        run.z = e * run.z + bf2f(s.z);
        run.w = e * run.w + bf2f(s.w);
    }
    *(float4*)(out_final + idx) = run;
}

// ---------------- Y = Y_diag + Y_off + D*X via MFMA, bf16 out ----------------
__global__ __launch_bounds__(256)
void y_mfma_k(const ushort_t* __restrict__ xBC, const float* __restrict__ dt_sp,
              const float* __restrict__ cumA, const ushort_t* __restrict__ CBT,
              const ushort_t* __restrict__ pref, const float* __restrict__ D_param,
              ushort_t* __restrict__ Y)
{
    int bi = blockIdx.x;                 // b*1024 + c*32 + h
    int h = bi & 31, c = (bi >> 5) & 31, b = bi >> 10;
    __shared__ ushort_t Wm[64 * 72];     // [l][s] masked decay*CBT*dt[s]
    __shared__ ushort_t XT[64 * 72];     // [p][s] raw X
    __shared__ ushort_t Cd[64 * 136];    // [l][n] C*exp(cA)
    __shared__ ushort_t Sp[64 * 136];    // [p][n] bf16 prefix state
    __shared__ float sCA[64];
    __shared__ float sdt[64];
    int t = threadIdx.x, r = t >> 2, q = t & 3;
    const float* cA = cumA + (size_t)((b*NH + h)*NCH + c) * 64;
    if (t < 64) {
        sCA[t] = cA[t];
        sdt[t] = dt_sp[(b * LSEQ + c * BLK + t) * NH + h];
    }
    __syncthreads();
    size_t row = (size_t)(b * LSEQ + c * BLK + r);
    const ushort_t* xb = xBC + row * CONVD;
    float myA = sCA[r], eC = __expf(myA);
    const ushort_t* cbt = CBT + (size_t)(b*NCH + c) * 4096 + r * 64 + q * 16;
    {
        ushortx8 c0 = *(const ushortx8*)(cbt);
        ushortx8 c1 = *(const ushortx8*)(cbt + 8);
        ushortx8 w0, w1;
#pragma unroll
        for (int j = 0; j < 8; ++j) {
            int s0 = q*16 + j, s1 = q*16 + 8 + j;
            float v0 = (s0 <= r) ? bf2f(c0[j]) * __expf(myA - sCA[s0]) * sdt[s0] : 0.f;
            float v1 = (s1 <= r) ? bf2f(c1[j]) * __expf(myA - sCA[s1]) * sdt[s1] : 0.f;
            w0[j] = f2bf(v0); w1[j] = f2bf(v1);
        }
        *(ushortx8*)&Wm[r*72 + q*16] = w0;
        *(ushortx8*)&Wm[r*72 + q*16 + 8] = w1;
    }
#pragma unroll
    for (int jj = 0; jj < 4; ++jj) {
        ushort4 v = *(const ushort4*)(xb + h*HP + q*16 + jj*4);
        int p0 = q*16 + jj*4;
        XT[(p0+0)*72 + r] = v.x; XT[(p0+1)*72 + r] = v.y;
        XT[(p0+2)*72 + r] = v.z; XT[(p0+3)*72 + r] = v.w;
    }
#pragma unroll
    for (int jj = 0; jj < 8; ++jj) {
        ushort4 v = *(const ushort4*)(xb + DI + NS + q*32 + jj*4);
        int n0 = q*32 + jj*4;
        ushort4 o;
        o.x = f2bf(bf2f(v.x)*eC); o.y = f2bf(bf2f(v.y)*eC);
        o.z = f2bf(bf2f(v.z)*eC); o.w = f2bf(bf2f(v.w)*eC);
        *(ushort4*)&Cd[r*136 + n0] = o;
    }
    const ushort_t* pr = pref + (size_t)((b*NCH + c)*NH + h) * 8192 + r * 128;
#pragma unroll
    for (int jj = 0; jj < 4; ++jj) {
        ushortx8 v = *(const ushortx8*)(pr + q*32 + jj*8);
        *(ushortx8*)&Sp[r*136 + q*32 + jj*8] = v;
    }
    __syncthreads();
    int ln = t & 63, w = t >> 6;
    int wm = (w >> 1) * 32, wn = (w & 1) * 32;   // l-span 32, p-span 32
    int fr = ln & 15;
    f32x4 acc[2][2] = {};
#pragma unroll
    for (int ks = 0; ks < 2; ++ks) {            // Y_diag over s (K=64)
        int koff = ks*32 + (ln >> 4) * 8;
        bf16x8 af[2], bv[2];
#pragma unroll
        for (int mt = 0; mt < 2; ++mt) af[mt] = *(const bf16x8*)&Wm[(wm + mt*16 + fr)*72 + koff];
#pragma unroll
        for (int nt = 0; nt < 2; ++nt) bv[nt] = *(const bf16x8*)&XT[(wn + nt*16 + fr)*72 + koff];
#pragma unroll
        for (int mt = 0; mt < 2; ++mt)
#pragma unroll
            for (int nt = 0; nt < 2; ++nt)
                acc[mt][nt] = __builtin_amdgcn_mfma_f32_16x16x32_bf16(af[mt], bv[nt], acc[mt][nt], 0, 0, 0);
    }
#pragma unroll
    for (int ks = 0; ks < 4; ++ks) {            // Y_off over n (K=128)
        int koff = ks*32 + (ln >> 4) * 8;
        bf16x8 af[2], bv[2];
#pragma unroll
        for (int mt = 0; mt < 2; ++mt) af[mt] = *(const bf16x8*)&Cd[(wm + mt*16 + fr)*136 + koff];
#pragma unroll
        for (int nt = 0; nt < 2; ++nt) bv[nt] = *(const bf16x8*)&Sp[(wn + nt*16 + fr)*136 + koff];
#pragma unroll
        for (int mt = 0; mt < 2; ++mt)
#pragma unroll
            for (int nt = 0; nt < 2; ++nt)
                acc[mt][nt] = __builtin_amdgcn_mfma_f32_16x16x32_bf16(af[mt], bv[nt], acc[mt][nt], 0, 0, 0);
    }
    float Dh = D_param[h];
    int crow = (ln >> 4) * 4, ccol = ln & 15;
#pragma unroll
    for (int mt = 0; mt < 2; ++mt)
#pragma unroll
        for (int nt = 0; nt < 2; ++nt)
#pragma unroll
            for (int i = 0; i < 4; ++i) {
                int li = wm + mt*16 + crow + i;
                int p  = wn + nt*16 + ccol;
                size_t rr = (size_t)(b*LSEQ + c*BLK + li);
                float xv = bf2f(XT[p*72 + li]);   // X from LDS, not HBM
                Y[rr * DI + h*HP + p] = f2bf(acc[mt][nt][i] + Dh * xv);
            }
}

// ---------------- RMSNorm + sigmoid(z) gate (bf16 in) -> bf16 ----------------
__global__ __launch_bounds__(256)
void rms_gate_k(const ushort_t* __restrict__ zx, const float* __restrict__ norm_w,
                const ushort_t* __restrict__ Y, ushort_t* __restrict__ Yb)
{
    int tk = blockIdx.x, t = threadIdx.x;
    const ushort_t* rowp = Y + (size_t)tk * DI + t*8;
    ushortx8 v = *(const ushortx8*)rowp;
    float f[8];
    float ss = 0.f;
#pragma unroll
    for (int i = 0; i < 8; ++i) { f[i] = bf2f(v[i]); ss += f[i]*f[i]; }
#pragma unroll
    for (int off = 32; off > 0; off >>= 1) ss += __shfl_xor(ss, off, 64);
    __shared__ float sw[4];
    __shared__ float stot;
    if ((t & 63) == 0) sw[t >> 6] = ss;
    __syncthreads();
    if (t == 0) stot = rsqrtf((sw[0]+sw[1]+sw[2]+sw[3]) * (1.f/DI) + 1.1920929e-07f);
    __syncthreads();
    float scale = stot;
    const ushort_t* zr = zx + (size_t)tk * PROJ + t*8;
    ushortx8 z = *(const ushortx8*)zr;
    float4 w0 = *(const float4*)(norm_w + t*8);
    float4 w1 = *(const float4*)(norm_w + t*8 + 4);
    float wv[8] = {w0.x,w0.y,w0.z,w0.w,w1.x,w1.y,w1.z,w1.w};
    ushortx8 o;
#pragma unroll
    for (int i = 0; i < 8; ++i)
        o[i] = f2bf(f[i]*scale*wv[i] / (1.f+__expf(-bf2f(z[i]))));
    *(ushortx8*)(Yb + (size_t)tk * DI + t*8) = o;
}

extern "C" void kernel_launch(void* const* d_in, const int* in_sizes, int n_in,
                              void* d_out, int out_size, void* d_ws, size_t ws_size,
                              hipStream_t stream)
{
    const float* x        = (const float*)d_in[0];
    const float* init_st  = (const float*)d_in[1];
    const float* in_proj  = (const float*)d_in[2];
    const float* conv_w   = (const float*)d_in[3];
    const float* A_log    = (const float*)d_in[4];
    const float* dt_bias  = (const float*)d_in[5];
    const float* D_param  = (const float*)d_in[6];
    const float* norm_w   = (const float*)d_in[7];
    const float* out_proj = (const float*)d_in[8];
    float* out = (float*)d_out;

    ushort_t* zx_bf  = (ushort_t*)d_ws;                       // TTOK*PROJ
    ushort_t* xBC_bf = zx_bf + (size_t)TTOK*PROJ;             // TTOK*CONVD
    float* dt_sp  = (float*)(xBC_bf + (size_t)TTOK*CONVD);    // TTOK*NH
    float* cumA   = dt_sp  + (size_t)TTOK*NH;                 // 131072
    ushort_t* CBTb = (ushort_t*)(cumA + (size_t)TTOK*NH);     // 262144 bf16
    ushort_t* states = CBTb + 262144;                         // 16777216 (bf16)
    ushort_t* pref = states + 16777216;                       // 16777216 (bf16)
    float* Yreg   = (float*)(pref + 16777216);                // region
    ushort_t* opw_bf = (ushort_t*)(Yreg + (size_t)TTOK*DI);   // DM*DI
    ushort_t* Y_bf   = (ushort_t*)Yreg;                       // TTOK*DI bf16
    ushort_t* xb_bf  = (ushort_t*)Yreg;                       // TTOK*DM (alias, dead after gemm1)
    ushort_t* ipw_bf = xb_bf + (size_t)TTOK*DM;               // PROJ*DM (alias, dead after gemm1)
    ushort_t* Yb_bf  = xBC_bf;                                // alias, used after y_mfma

    const int nc = (TTOK*DM + PROJ*DM + DM*DI) / (256*8);
    cast_all_k<<<nc, 256, 0, stream>>>(x, in_proj, out_proj, xb_bf, ipw_bf, opw_bf);
    hgemm_nt<128,128,0,1><<<((PROJ+127)/128)*(TTOK/128), 256, 0, stream>>>(xb_bf, ipw_bf, zx_bf, nullptr, TTOK, PROJ, DM);
    mid1_k<<<NCONVB + BATCH*NH*NCH/4, 256, 0, stream>>>(zx_bf, conv_w, dt_bias, A_log, xBC_bf, dt_sp, cumA);
    mid2_k<<<64 + BATCH*NCH*NH, 256, 0, stream>>>(xBC_bf, dt_sp, cumA, CBTb, states);
    scan_k<<<(BATCH*NH*HP*NS)/(256*4), 256, 0, stream>>>(init_st, cumA, states, pref, out + (size_t)TTOK*DM);
    y_mfma_k<<<BATCH*NCH*NH, 256, 0, stream>>>(xBC_bf, dt_sp, cumA, CBTb, pref, D_param, Y_bf);
    rms_gate_k<<<TTOK, 256, 0, stream>>>(zx_bf, norm_w, Y_bf, Yb_bf);
    hgemm_nt<128,64,1,0><<<(DM/64)*(TTOK/128), 256, 0, stream>>>(Yb_bf, opw_bf, out, x, TTOK, DM, DI);
}